// Round 4
// baseline (202.570 us; speedup 1.0000x reference)
//
#include <hip/hip_runtime.h>

// conv_layer: out[b,v,o] = sum_{j<7,c<64} x[b, neigh[v*7+j], c] * W[o, j*64+c] + bias[o]
// B=2, V=163842, C_IN=C_OUT=64, K=448. bf16 MFMA gather-GEMM.
// R4: gather via global_load_lds DMA into per-wave LDS ring (3 slots x 2KB),
//     counted vmcnt(4) pipeline -> outstanding loads no longer VGPR-limited.

constexpr int V_ICO   = 163842;
constexpr int M_TOTAL = 2 * V_ICO;        // 327684
constexpr int X_ELEMS = M_TOTAL * 64;     // 20,971,776
constexpr int W_ELEMS = 64 * 448;         // 28,672
constexpr int XCH     = X_ELEMS / 8;      // 16B bf16 chunks of x
constexpr int WCH     = W_ELEMS / 8;      // 3584

typedef __attribute__((ext_vector_type(4))) float          f32x4;
typedef __attribute__((ext_vector_type(4))) unsigned int   u32x4;
typedef __attribute__((ext_vector_type(8))) unsigned short u16x8;
typedef __attribute__((ext_vector_type(8))) __bf16         bf16x8;

union BF8 { u32x4 q; u16x8 u; bf16x8 v; };

#define AS1 __attribute__((address_space(1)))
#define AS3 __attribute__((address_space(3)))
#define WAITV(N) asm volatile("s_waitcnt vmcnt(" #N ")" ::: "memory")
#define WAITL0   asm volatile("s_waitcnt lgkmcnt(0)" ::: "memory")

static __device__ __forceinline__ unsigned short f2bf(float f) {
  unsigned int t = __float_as_uint(f);
  t += 0x7FFFu + ((t >> 16) & 1u);   // round-to-nearest-even
  return (unsigned short)(t >> 16);
}

static __device__ __forceinline__ u32x4 cvt8(f32x4 a, f32x4 b) {
  BF8 r;
  r.u[0] = f2bf(a[0]); r.u[1] = f2bf(a[1]); r.u[2] = f2bf(a[2]); r.u[3] = f2bf(a[3]);
  r.u[4] = f2bf(b[0]); r.u[5] = f2bf(b[1]); r.u[6] = f2bf(b[2]); r.u[7] = f2bf(b[3]);
  return r.q;
}

// fp32 -> bf16 for x (and W appended). One 16B-out chunk per thread.
__global__ __launch_bounds__(256)
void cvt_x_w(const float* __restrict__ x, const float* __restrict__ W,
             u32x4* __restrict__ xbf, u32x4* __restrict__ wbf) {
  const int i = blockIdx.x * blockDim.x + threadIdx.x;
  if (i >= XCH + WCH) return;
  const f32x4* src;
  u32x4* dst;
  if (i < XCH) {
    src = reinterpret_cast<const f32x4*>(x) + 2 * (size_t)i;
    dst = xbf + i;
  } else {
    const int k = i - XCH;
    src = reinterpret_cast<const f32x4*>(W) + 2 * (size_t)k;
    dst = wbf + k;
  }
  f32x4 f0 = src[0], f1 = src[1];
  *dst = cvt8(f0, f1);
}

__global__ __launch_bounds__(256)
void cvt_w_only(const float* __restrict__ W, u32x4* __restrict__ wbf) {
  const int i = blockIdx.x * blockDim.x + threadIdx.x;
  if (i < WCH) {
    const f32x4* src = reinterpret_cast<const f32x4*>(W) + 2 * (size_t)i;
    f32x4 f0 = src[0], f1 = src[1];
    wbf[i] = cvt8(f0, f1);
  }
}

// Main gather-GEMM. Block = 1024 threads = 16 waves; wave owns 16 output rows,
// all 64 out channels. LDS: W 57344 B + gather ring 16*3*2048 = 98304 B ->
// 155648 B -> 1 block/CU (16 waves). Gather DMA'd to LDS, no VGPR pressure.
template <int XBF, int WPRE>
__global__ __launch_bounds__(1024, 4)
void gather_mm(const float* __restrict__ x32, const unsigned short* __restrict__ x16,
               const int* __restrict__ neigh,
               const float* __restrict__ W32, const unsigned short* __restrict__ W16,
               const float* __restrict__ bias, float* __restrict__ out) {
  __shared__ __align__(16) unsigned short Wlds[WCH * 8];   // 57344 B, fragment-ordered
  __shared__ __align__(16) char gbuf[16 * 3 * 2048];       // 98304 B gather ring

  const int tid  = threadIdx.x;
  const int w    = tid >> 6;      // wave 0..15
  const int lane = tid & 63;
  const int r    = lane & 15;     // A-tile row / out-channel low bits
  const int g    = lane >> 4;     // k-group 0..3
  const int m0   = blockIdx.x * 256 + w * 16;

  int mA = m0 + r;
  if (mA > M_TOTAL - 1) mA = M_TOTAL - 1;   // clamp for safe index loads
  const int bA = (mA >= V_ICO) ? 1 : 0;
  const int vA = mA - bA * V_ICO;

  int nofs[7];
#pragma unroll
  for (int j = 0; j < 7; ++j) nofs[j] = neigh[vA * 7 + j];

  // Stage W, fragment-ordered: chunk i = (kc*4+nt)*64 + l holds
  // W[nt*16 + (l&15)][kc*32 + (l>>4)*8 .. +8].
  for (int i = tid; i < WCH; i += 1024) {
    const int kcnt = i >> 6;               // kc*4 + nt
    const int l    = i & 63;
    const int row  = ((kcnt & 3) << 4) | (l & 15);
    u32x4 val;
    if constexpr (WPRE) {
      const int c8 = ((kcnt >> 2) << 2) + (l >> 4);        // col/8
      val = reinterpret_cast<const u32x4*>(W16)[row * 56 + c8];
    } else {
      const int col = ((kcnt >> 2) << 5) + ((l >> 4) << 3);
      const f32x4* p = reinterpret_cast<const f32x4*>(W32 + row * 448 + col);
      val = cvt8(p[0], p[1]);
    }
    *reinterpret_cast<u32x4*>(&Wlds[(size_t)i * 8]) = val;
  }
  __syncthreads();
  if (m0 >= M_TOTAL) return;      // after the only barrier: legal

  const unsigned short* wp = Wlds + (lane << 3);   // + (kc*4+nt)*512 imm offsets
  char* gs = &gbuf[w * 3 * 2048];                  // per-wave ring: slots 0/2048/4096

  const f32x4 zero = {0.f, 0.f, 0.f, 0.f};
  f32x4 acc0 = zero, acc1 = zero, acc2 = zero, acc3 = zero;

#define MFMA_NT(af, nt, kc)                                                 \
    acc##nt = __builtin_amdgcn_mfma_f32_16x16x32_bf16(                      \
        af.v,                                                               \
        *reinterpret_cast<const bf16x8*>(wp + ((kc) * 4 + (nt)) * 512),     \
        acc##nt, 0, 0, 0)

#define MFMA_8(dl, dh, j) do {                                              \
    __builtin_amdgcn_s_setprio(1);                                          \
    MFMA_NT(dl, 0, 2*(j));   MFMA_NT(dl, 1, 2*(j));                         \
    MFMA_NT(dl, 2, 2*(j));   MFMA_NT(dl, 3, 2*(j));                         \
    MFMA_NT(dh, 0, 2*(j)+1); MFMA_NT(dh, 1, 2*(j)+1);                       \
    MFMA_NT(dh, 2, 2*(j)+1); MFMA_NT(dh, 3, 2*(j)+1);                       \
    __builtin_amdgcn_s_setprio(0);                                          \
  } while (0)

  if constexpr (XBF) {
    const unsigned short* xb = x16 + (size_t)bA * V_ICO * 64 + (g << 3);

    // DMA 16 rows' kc-pair into this wave's slot: lane l -> slot + l*16.
#define ISSUE_J(so, j) do {                                                  \
      const unsigned short* rp_ = xb + (size_t)nofs[j] * 64;                 \
      __builtin_amdgcn_global_load_lds((const AS1 unsigned int*)rp_,         \
          (AS3 unsigned int*)(gs + (so)), 16, 0, 0);                         \
      __builtin_amdgcn_global_load_lds((const AS1 unsigned int*)(rp_ + 32),  \
          (AS3 unsigned int*)(gs + (so) + 1024), 16, 0, 0);                  \
    } while (0)

#define COMP_J(so, j) do {                                                   \
      BF8 dl, dh;                                                            \
      dl.q = *reinterpret_cast<const u32x4*>(gs + (so) + (lane << 4));       \
      dh.q = *reinterpret_cast<const u32x4*>(gs + (so) + 1024 + (lane << 4));\
      MFMA_8(dl, dh, j);                                                     \
    } while (0)

    WAITV(0);                       // pin vmcnt baseline
    ISSUE_J(0, 0); ISSUE_J(2048, 1); ISSUE_J(4096, 2);
    WAITV(4); COMP_J(0, 0);    WAITL0; ISSUE_J(0, 3);
    WAITV(4); COMP_J(2048, 1); WAITL0; ISSUE_J(2048, 4);
    WAITV(4); COMP_J(4096, 2); WAITL0; ISSUE_J(4096, 5);
    WAITV(4); COMP_J(0, 3);    WAITL0; ISSUE_J(0, 6);
    WAITV(4); COMP_J(2048, 4);
    WAITV(2); COMP_J(4096, 5);
    WAITV(0); COMP_J(0, 6);
#undef ISSUE_J
#undef COMP_J
  } else {
    // fp32 fallback (unused when ws fits): per-lane loads, depth-1.
    const float* xb32 = x32 + (size_t)bA * V_ICO * 64 + (g << 3);
#pragma unroll
    for (int j = 0; j < 7; ++j) {
      const float* rp = xb32 + (size_t)nofs[j] * 64;
      const f32x4* p0 = reinterpret_cast<const f32x4*>(rp);
      const f32x4* p1 = reinterpret_cast<const f32x4*>(rp + 32);
      BF8 dl, dh;
      dl.q = cvt8(p0[0], p0[1]);
      dh.q = cvt8(p1[0], p1[1]);
      MFMA_8(dl, dh, j);
    }
  }
#undef MFMA_NT
#undef MFMA_8

  // C/D layout: col = lane&15 (= r -> out channel), row = g*4 + reg.
  const float bv0 = bias[r], bv1 = bias[16 + r], bv2 = bias[32 + r], bv3 = bias[48 + r];
  const bool full = (m0 + 16 <= M_TOTAL);
#pragma unroll
  for (int q2 = 0; q2 < 4; ++q2) {
    const int mS = m0 + (g << 2) + q2;
    if (full || mS < M_TOTAL) {
      float* o = out + (size_t)mS * 64;
      __builtin_nontemporal_store(acc0[q2] + bv0, o + r);
      __builtin_nontemporal_store(acc1[q2] + bv1, o + 16 + r);
      __builtin_nontemporal_store(acc2[q2] + bv2, o + 32 + r);
      __builtin_nontemporal_store(acc3[q2] + bv3, o + 48 + r);
    }
  }
}

extern "C" void kernel_launch(void* const* d_in, const int* in_sizes, int n_in,
                              void* d_out, int out_size, void* d_ws, size_t ws_size,
                              hipStream_t stream) {
  const float* x    = (const float*)d_in[0];
  const int*   nbr  = (const int*)d_in[1];
  const float* W    = (const float*)d_in[2];
  const float* bias = (const float*)d_in[3];
  float* out = (float*)d_out;

  const size_t xbf_bytes = (size_t)X_ELEMS * 2;
  const size_t wbf_bytes = (size_t)W_ELEMS * 2;
  const int grid_main = (M_TOTAL + 255) / 256;    // 1281

  if (ws_size >= xbf_bytes + wbf_bytes) {
    u32x4* xbf = (u32x4*)d_ws;
    u32x4* wbf = (u32x4*)((char*)d_ws + xbf_bytes);
    hipLaunchKernelGGL(cvt_x_w, dim3((XCH + WCH + 255) / 256), dim3(256), 0, stream,
                       x, W, xbf, wbf);
    hipLaunchKernelGGL((gather_mm<1, 1>), dim3(grid_main), dim3(1024), 0, stream,
                       x, (const unsigned short*)xbf, nbr,
                       W, (const unsigned short*)wbf, bias, out);
  } else if (ws_size >= wbf_bytes) {
    u32x4* wbf = (u32x4*)d_ws;
    hipLaunchKernelGGL(cvt_w_only, dim3((WCH + 255) / 256), dim3(256), 0, stream, W, wbf);
    hipLaunchKernelGGL((gather_mm<0, 1>), dim3(grid_main), dim3(1024), 0, stream,
                       x, nullptr, nbr, W, (const unsigned short*)wbf, bias, out);
  } else {
    hipLaunchKernelGGL((gather_mm<0, 0>), dim3(grid_main), dim3(1024), 0, stream,
                       x, nullptr, nbr, W, nullptr, bias, out);
  }
}